// Round 14
// baseline (354.407 us; speedup 1.0000x reference)
//
#include <hip/hip_runtime.h>
#include <hip/hip_cooperative_groups.h>

namespace cg = cooperative_groups;

#define WIDTH 128
#define SLOPE 0.01f
#define FBM 64
#define CBLK 512          // coop grid blocks

typedef __attribute__((ext_vector_type(8))) short short8;
typedef __attribute__((ext_vector_type(4))) float f32x4;

__device__ __forceinline__ unsigned short f2bf(float f) {
    unsigned b = __float_as_uint(f);
    b += 0x7FFFu + ((b >> 16) & 1u);   // round-to-nearest-even
    return (unsigned short)(b >> 16);
}
__device__ __forceinline__ float4 upk(uint2 u) {   // 4 bf16 -> 4 f32 (exact)
    float4 r;
    r.x = __uint_as_float(u.x << 16);
    r.y = __uint_as_float(u.x & 0xFFFF0000u);
    r.z = __uint_as_float(u.y << 16);
    r.w = __uint_as_float(u.y & 0xFFFF0000u);
    return r;
}
__device__ __forceinline__ float4 fmin4(float4 a, float4 b) {
    return make_float4(fminf(a.x, b.x), fminf(a.y, b.y),
                       fminf(a.z, b.z), fminf(a.w, b.w));
}
// XOR-swizzled LDS byte offset for row-major [64][512B] tile (T2/G4)
__device__ __forceinline__ int swz(int lr, int bc) {
    return lr * 512 + (bc ^ ((lr & 7) << 4));
}

// ============ ONE cooperative kernel: prep + hist + scan + scatter =========
// phase0: xsb=bf16(x_src) | Wt fold | hist+rank   (independent, grid-stride)
// phase1: per-512-chunk sums    phase2: scan sums (block 0)
// phase3: offsets               phase4: scatter csr
__global__ void __launch_bounds__(256) csr_coop_kernel(
        const float* __restrict__ x_src, const float* __restrict__ W,
        const int* __restrict__ e,
        unsigned short* __restrict__ xsb, unsigned short* __restrict__ Wt,
        unsigned* __restrict__ counts, int* __restrict__ rank,
        int* __restrict__ offsets, int* __restrict__ csr,
        unsigned* __restrict__ bsums, unsigned* __restrict__ bbase,
        int NS, int E, int M, int NB, int use_xsb) {
    cg::grid_group grid = cg::this_grid();
    __shared__ unsigned s[256];
    __shared__ unsigned wsx[4];
    int tid = threadIdx.x;
    int gsize = gridDim.x * 256;
    int gthread = blockIdx.x * 256 + tid;
    int lane = tid & 63, w = tid >> 6;

    // ---- phase 0a: xsb = bf16(x_src), float4 units ----
    if (use_xsb) {
        for (int i = gthread; i < NS * 32; i += gsize) {
            float4 v = reinterpret_cast<const float4*>(x_src)[i];
            ushort4 o;
            o.x = f2bf(v.x); o.y = f2bf(v.y); o.z = f2bf(v.z); o.w = f2bf(v.w);
            *reinterpret_cast<ushort4*>(xsb + (size_t)i * 4) = o;
        }
    }
    // ---- phase 0b: W fold+transpose: W'=[W0+W1; -W1], Wt[n][k] ----
    for (int t = gthread; t < 128 * 64; t += gsize) {
        int n = t & 127, kc = t >> 7;
        ushort4 o;
        unsigned short* op = &o.x;
        #pragma unroll
        for (int j = 0; j < 4; ++j) {
            int k = kc * 4 + j;
            float v;
            if (k < 128) v = W[(size_t)k * 128 + n] + W[(size_t)(k + 128) * 128 + n];
            else         v = -W[(size_t)k * 128 + n];
            op[j] = f2bf(v);
        }
        *reinterpret_cast<ushort4*>(Wt + (size_t)n * 256 + kc * 4) = o;
    }
    // ---- phase 0c: hist + rank ----
    for (int i = gthread; i < E; i += gsize) {
        int dst = e[E + i];
        rank[i] = (int)atomicAdd(&counts[dst], 1u);
    }
    grid.sync();

    // ---- phase 1: per-chunk (512) sums ----
    for (int b = blockIdx.x; b < NB; b += gridDim.x) {
        int base = b * 512;
        int i0 = base + tid, i1 = base + 256 + tid;
        unsigned v = 0;
        if (i0 < M) v += counts[i0];
        if (i1 < M) v += counts[i1];
        for (int d = 32; d > 0; d >>= 1) v += __shfl_down(v, d);
        if (lane == 0) wsx[w] = v;
        __syncthreads();
        if (tid == 0) bsums[b] = wsx[0] + wsx[1] + wsx[2] + wsx[3];
        __syncthreads();
    }
    grid.sync();

    // ---- phase 2: exclusive scan of NB (<=256) chunk sums, block 0 ----
    if (blockIdx.x == 0) {
        unsigned v = (tid < NB) ? bsums[tid] : 0u;
        s[tid] = v;
        __syncthreads();
        for (int off = 1; off < 256; off <<= 1) {
            unsigned n = (tid >= off) ? s[tid - off] : 0u;
            __syncthreads();
            s[tid] += n;
            __syncthreads();
        }
        if (tid < NB) bbase[tid] = s[tid] - v;
        if (tid == 255) offsets[M] = (int)s[255];
    }
    grid.sync();

    // ---- phase 3: final offsets (each thread: 2 consecutive counts) ----
    for (int b = blockIdx.x; b < NB; b += gridDim.x) {
        int base = b * 512;
        int i0 = base + 2 * tid;
        unsigned c0 = (i0 < M) ? counts[i0] : 0u;
        unsigned c1 = (i0 + 1 < M) ? counts[i0 + 1] : 0u;
        unsigned pair = c0 + c1;
        unsigned v = pair;
        for (int d = 1; d < 64; d <<= 1) {
            unsigned n = __shfl_up(v, d);
            if (lane >= d) v += n;
        }
        if (lane == 63) wsx[w] = v;
        __syncthreads();
        unsigned wb = 0;
        for (int k = 0; k < w; ++k) wb += wsx[k];
        unsigned excl = bbase[b] + wb + v - pair;
        if (i0 < M) offsets[i0] = (int)excl;
        if (i0 + 1 < M) offsets[i0 + 1] = (int)(excl + c0);
        __syncthreads();
    }
    grid.sync();

    // ---- phase 4: scatter ----
    for (int i = gthread; i < E; i += gsize) {
        int dst = e[E + i];
        csr[offsets[dst] + rank[i]] = e[i];
    }
}

// -------- 8-edge gather-min step for one row (2 edges/load, lane halves) ---
template<int XSB>
__device__ __forceinline__ void gstep(const float* xs_f,
                                      const unsigned short* xs_b,
                                      const int* csr, int p, int lim,
                                      int half, int cl, float4& mn) {
    int i0 = csr[min(p + 0, lim)];
    int i1 = csr[min(p + 1, lim)];
    int i2 = csr[min(p + 2, lim)];
    int i3 = csr[min(p + 3, lim)];
    int i4 = csr[min(p + 4, lim)];
    int i5 = csr[min(p + 5, lim)];
    int i6 = csr[min(p + 6, lim)];
    int i7 = csr[min(p + 7, lim)];
    int a0 = half ? i1 : i0;
    int a1 = half ? i3 : i2;
    int a2 = half ? i5 : i4;
    int a3 = half ? i7 : i6;
    float4 w0, w1, w2, w3;
    if (XSB) {
        uint2 u0 = *reinterpret_cast<const uint2*>(xs_b + (size_t)a0 * 128 + cl * 4);
        uint2 u1 = *reinterpret_cast<const uint2*>(xs_b + (size_t)a1 * 128 + cl * 4);
        uint2 u2 = *reinterpret_cast<const uint2*>(xs_b + (size_t)a2 * 128 + cl * 4);
        uint2 u3 = *reinterpret_cast<const uint2*>(xs_b + (size_t)a3 * 128 + cl * 4);
        w0 = upk(u0); w1 = upk(u1); w2 = upk(u2); w3 = upk(u3);
    } else {
        const float4* xs4 = reinterpret_cast<const float4*>(xs_f);
        w0 = xs4[(size_t)a0 * 32 + cl];
        w1 = xs4[(size_t)a1 * 32 + cl];
        w2 = xs4[(size_t)a2 * 32 + cl];
        w3 = xs4[(size_t)a3 * 32 + cl];
    }
    mn = fmin4(mn, fmin4(fmin4(w0, w1), fmin4(w2, w3)));
}

// ---------------- Fused (round-7 verbatim): gather-min -> LDS -> MFMA ------
template<int XSB>
__global__ __launch_bounds__(256, 4) void fused_kernel(
        const float* __restrict__ x_src,
        const unsigned short* __restrict__ xsb,
        const float* __restrict__ x_dst,
        const int* __restrict__ offsets,
        const int* __restrict__ csr,
        const unsigned short* __restrict__ Wt,
        const float* __restrict__ bias,
        float* __restrict__ out, int M) {
    __shared__ unsigned short At[FBM * 256];   // 32 KB
    char* Ab = reinterpret_cast<char*>(At);
    int tid = threadIdx.x;
    int lane = tid & 63;
    int wv = tid >> 6;
    int blockRow = blockIdx.x * FBM;

    #pragma unroll
    for (int i = 0; i < 8; ++i) {
        int u = tid + 256 * i;
        int lr = u >> 5;
        int c4 = u & 31;
        int gr = min(blockRow + lr, M - 1);
        float4 v = reinterpret_cast<const float4*>(x_dst)[(size_t)gr * 32 + c4];
        ushort4 o;
        o.x = f2bf(v.x); o.y = f2bf(v.y); o.z = f2bf(v.z); o.w = f2bf(v.w);
        *reinterpret_cast<ushort4*>(Ab + swz(lr, c4 * 8)) = o;
    }
    __syncthreads();

    int half = lane >> 5, cl = lane & 31;
    for (int j = 0; j < 4; ++j) {
        int lrb = wv * 16 + 4 * j;
        int beg0, beg1, beg2, beg3, end0, end1, end2, end3;
        {
            int r = __builtin_amdgcn_readfirstlane(blockRow + lrb);
            beg0 = (r + 0 < M) ? offsets[r + 0] : 0;
            end0 = (r + 0 < M) ? offsets[r + 1] : 0;
            beg1 = (r + 1 < M) ? offsets[r + 1] : 0;
            end1 = (r + 1 < M) ? offsets[r + 2] : 0;
            beg2 = (r + 2 < M) ? offsets[r + 2] : 0;
            end2 = (r + 2 < M) ? offsets[r + 3] : 0;
            beg3 = (r + 3 < M) ? offsets[r + 3] : 0;
            end3 = (r + 3 < M) ? offsets[r + 4] : 0;
        }
        float4 mn0 = make_float4(INFINITY, INFINITY, INFINITY, INFINITY);
        float4 mn1 = mn0, mn2 = mn0, mn3 = mn0;
        int p0 = beg0, p1 = beg1, p2 = beg2, p3 = beg3;
        while ((p0 < end0) | (p1 < end1) | (p2 < end2) | (p3 < end3)) {
            if (p0 < end0) { gstep<XSB>(x_src, xsb, csr, p0, end0 - 1, half, cl, mn0); p0 += 8; }
            if (p1 < end1) { gstep<XSB>(x_src, xsb, csr, p1, end1 - 1, half, cl, mn1); p1 += 8; }
            if (p2 < end2) { gstep<XSB>(x_src, xsb, csr, p2, end2 - 1, half, cl, mn2); p2 += 8; }
            if (p3 < end3) { gstep<XSB>(x_src, xsb, csr, p3, end3 - 1, half, cl, mn3); p3 += 8; }
        }
        mn0.x = fminf(mn0.x, __shfl_xor(mn0.x, 32));
        mn0.y = fminf(mn0.y, __shfl_xor(mn0.y, 32));
        mn0.z = fminf(mn0.z, __shfl_xor(mn0.z, 32));
        mn0.w = fminf(mn0.w, __shfl_xor(mn0.w, 32));
        mn1.x = fminf(mn1.x, __shfl_xor(mn1.x, 32));
        mn1.y = fminf(mn1.y, __shfl_xor(mn1.y, 32));
        mn1.z = fminf(mn1.z, __shfl_xor(mn1.z, 32));
        mn1.w = fminf(mn1.w, __shfl_xor(mn1.w, 32));
        mn2.x = fminf(mn2.x, __shfl_xor(mn2.x, 32));
        mn2.y = fminf(mn2.y, __shfl_xor(mn2.y, 32));
        mn2.z = fminf(mn2.z, __shfl_xor(mn2.z, 32));
        mn2.w = fminf(mn2.w, __shfl_xor(mn2.w, 32));
        mn3.x = fminf(mn3.x, __shfl_xor(mn3.x, 32));
        mn3.y = fminf(mn3.y, __shfl_xor(mn3.y, 32));
        mn3.z = fminf(mn3.z, __shfl_xor(mn3.z, 32));
        mn3.w = fminf(mn3.w, __shfl_xor(mn3.w, 32));

        {
            int lr = lrb + half;
            bool has = half ? (end1 > beg1) : (end0 > beg0);
            float4 m = half ? mn1 : mn0;
            ushort4 o;
            if (has) {
                o.x = f2bf(m.x); o.y = f2bf(m.y); o.z = f2bf(m.z); o.w = f2bf(m.w);
            } else {   // empty row: mn := xb  =>  h = xb@W0 exactly
                o = *reinterpret_cast<const ushort4*>(Ab + swz(lr, cl * 8));
            }
            *reinterpret_cast<ushort4*>(Ab + swz(lr, 256 + cl * 8)) = o;
        }
        {
            int lr = lrb + 2 + half;
            bool has = half ? (end3 > beg3) : (end2 > beg2);
            float4 m = half ? mn3 : mn2;
            ushort4 o;
            if (has) {
                o.x = f2bf(m.x); o.y = f2bf(m.y); o.z = f2bf(m.z); o.w = f2bf(m.w);
            } else {
                o = *reinterpret_cast<const ushort4*>(Ab + swz(lr, cl * 8));
            }
            *reinterpret_cast<ushort4*>(Ab + swz(lr, 256 + cl * 8)) = o;
        }
    }
    __syncthreads();

    int l15 = lane & 15;
    int q = lane >> 4;
    int ncol0 = wv * 32;

    f32x4 acc[4][2];
    #pragma unroll
    for (int t = 0; t < 4; ++t) {
        acc[t][0] = (f32x4){0.f, 0.f, 0.f, 0.f};
        acc[t][1] = (f32x4){0.f, 0.f, 0.f, 0.f};
    }
    size_t b0off = (size_t)(ncol0 + l15) * 256;
    size_t b1off = (size_t)(ncol0 + 16 + l15) * 256;

    #pragma unroll
    for (int s = 0; s < 8; ++s) {
        int koff = s * 32 + q * 8;
        short8 b0 = *reinterpret_cast<const short8*>(Wt + b0off + koff);
        short8 b1 = *reinterpret_cast<const short8*>(Wt + b1off + koff);
        #pragma unroll
        for (int t = 0; t < 4; ++t) {
            int lr = t * 16 + l15;
            short8 a = *reinterpret_cast<const short8*>(Ab + swz(lr, koff * 2));
            acc[t][0] = __builtin_amdgcn_mfma_f32_16x16x32_bf16(b0, a, acc[t][0], 0, 0, 0);
            acc[t][1] = __builtin_amdgcn_mfma_f32_16x16x32_bf16(b1, a, acc[t][1], 0, 0, 0);
        }
    }

    float4 bi[2];
    bi[0] = *reinterpret_cast<const float4*>(bias + ncol0 + q * 4);
    bi[1] = *reinterpret_cast<const float4*>(bias + ncol0 + 16 + q * 4);
    #pragma unroll
    for (int t = 0; t < 4; ++t) {
        int lr = t * 16 + l15;
        int row = blockRow + lr;
        if (row < M) {
            #pragma unroll
            for (int u = 0; u < 2; ++u) {
                int col = ncol0 + u * 16 + q * 4;
                uint2 xu = *reinterpret_cast<const uint2*>(Ab + swz(lr, col * 2));
                float4 xb = upk(xu);
                float4 o;
                float h;
                h = acc[t][u][0] + bi[u].x; o.x = xb.x + (h > 0.f ? h : SLOPE * h);
                h = acc[t][u][1] + bi[u].y; o.y = xb.y + (h > 0.f ? h : SLOPE * h);
                h = acc[t][u][2] + bi[u].z; o.z = xb.z + (h > 0.f ? h : SLOPE * h);
                h = acc[t][u][3] + bi[u].w; o.w = xb.w + (h > 0.f ? h : SLOPE * h);
                *reinterpret_cast<float4*>(out + (size_t)row * 128 + col) = o;
            }
        }
    }
}

extern "C" void kernel_launch(void* const* d_in, const int* in_sizes, int n_in,
                              void* d_out, int out_size, void* d_ws, size_t ws_size,
                              hipStream_t stream) {
    const float* x_src = (const float*)d_in[0];
    const float* x_dst = (const float*)d_in[1];
    const int*   e     = (const int*)d_in[2];
    const float* W     = (const float*)d_in[3];
    const float* bias  = (const float*)d_in[4];
    float* out = (float*)d_out;

    int NS = in_sizes[0] / WIDTH;   // 100000 src nodes
    int E  = in_sizes[2] / 2;       // 800000
    int M  = in_sizes[1] / WIDTH;   // 100000 dst nodes
    int NB = (M + 511) / 512;       // 196 (<= 256)

    // ws: xsb bf16[NS*128] | Wt bf16[128*256] | counts[M] | offsets[M+1] |
    //     rank[E] | csr[E] | bsums[NB] | bbase[NB]    (~33 MB)
    unsigned short* xsb = (unsigned short*)d_ws;
    unsigned short* Wt  = xsb + (size_t)NS * WIDTH;
    unsigned* counts  = (unsigned*)(Wt + 128 * 256);
    int*      offsets = (int*)(counts + M);
    int*      rank    = offsets + (M + 1);
    int*      csr     = rank + E;
    unsigned* bsums   = (unsigned*)(csr + E);
    unsigned* bbase   = bsums + NB;
    size_t need = (char*)(bbase + NB) - (char*)d_ws;
    int use_xsb = (ws_size >= need) ? 1 : 0;
    if (!use_xsb) {   // fallback: no xsb; shift layout to skip it
        Wt = (unsigned short*)d_ws;
        counts  = (unsigned*)(Wt + 128 * 256);
        offsets = (int*)(counts + M);
        rank    = offsets + (M + 1);
        csr     = rank + E;
        bsums   = (unsigned*)(csr + E);
        bbase   = bsums + NB;
    }

    hipMemsetAsync(counts, 0, (size_t)M * sizeof(unsigned), stream);

    void* args[] = {
        (void*)&x_src, (void*)&W, (void*)&e,
        (void*)&xsb, (void*)&Wt,
        (void*)&counts, (void*)&rank, (void*)&offsets, (void*)&csr,
        (void*)&bsums, (void*)&bbase,
        (void*)&NS, (void*)&E, (void*)&M, (void*)&NB, (void*)&use_xsb
    };
    hipLaunchCooperativeKernel((void*)csr_coop_kernel, dim3(CBLK), dim3(256),
                               args, 0, stream);

    int fblocks = (M + FBM - 1) / FBM;   // 1563
    if (use_xsb)
        fused_kernel<1><<<fblocks, 256, 0, stream>>>(x_src, xsb, x_dst, offsets,
                                                     csr, Wt, bias, out, M);
    else
        fused_kernel<0><<<fblocks, 256, 0, stream>>>(x_src, xsb, x_dst, offsets,
                                                     csr, Wt, bias, out, M);
}

// Round 15
// 138.917 us; speedup vs baseline: 2.5512x; 2.5512x over previous
//
#include <hip/hip_runtime.h>

#define WIDTH 128
#define SLOPE 0.01f
#define FBM 64

typedef __attribute__((ext_vector_type(8))) short short8;
typedef __attribute__((ext_vector_type(4))) float f32x4;

__device__ __forceinline__ unsigned short f2bf(float f) {
    unsigned b = __float_as_uint(f);
    b += 0x7FFFu + ((b >> 16) & 1u);   // round-to-nearest-even
    return (unsigned short)(b >> 16);
}
__device__ __forceinline__ float4 upk(uint2 u) {   // 4 bf16 -> 4 f32 (exact)
    float4 r;
    r.x = __uint_as_float(u.x << 16);
    r.y = __uint_as_float(u.x & 0xFFFF0000u);
    r.z = __uint_as_float(u.y << 16);
    r.w = __uint_as_float(u.y & 0xFFFF0000u);
    return r;
}
__device__ __forceinline__ float4 fmin4(float4 a, float4 b) {
    return make_float4(fminf(a.x, b.x), fminf(a.y, b.y),
                       fminf(a.z, b.z), fminf(a.w, b.w));
}
// XOR-swizzled LDS byte offset for row-major [64][512B] tile (T2/G4)
__device__ __forceinline__ int swz(int lr, int bc) {
    return lr * 512 + (bc ^ ((lr & 7) << 4));
}

// ---------------- prep: xsb = bf16(x_src)  |  hist+rank  |  W fold ---------
__global__ void prep_kernel(const float* __restrict__ x_src,
                            const float* __restrict__ W,
                            const int* __restrict__ e,
                            unsigned short* __restrict__ xsb,
                            unsigned short* __restrict__ Wt,
                            unsigned* __restrict__ counts,
                            int* __restrict__ rank,
                            int NS, int E, int nconv, int nhist) {
    int b = blockIdx.x;
    if (b < nconv) {
        int i = b * 256 + threadIdx.x;          // float4 units over x_src
        if (i < NS * 32) {
            float4 v = reinterpret_cast<const float4*>(x_src)[i];
            ushort4 o;
            o.x = f2bf(v.x); o.y = f2bf(v.y); o.z = f2bf(v.z); o.w = f2bf(v.w);
            *reinterpret_cast<ushort4*>(xsb + (size_t)i * 4) = o;
        }
    } else if (b < nconv + nhist) {
        int i = (b - nconv) * 256 + threadIdx.x;
        if (i < E) {
            int dst = e[E + i];
            rank[i] = (int)atomicAdd(&counts[dst], 1u);
        }
    } else {
        int t = (b - nconv - nhist) * 256 + threadIdx.x;
        if (t < 128 * 64) {
            int n = t & 127, kc = t >> 7;       // k = kc*4+j over 0..255
            ushort4 o;
            unsigned short* op = &o.x;
            #pragma unroll
            for (int j = 0; j < 4; ++j) {
                int k = kc * 4 + j;
                float v;
                if (k < 128) v = W[(size_t)k * 128 + n] + W[(size_t)(k + 128) * 128 + n];
                else         v = -W[(size_t)k * 128 + n];
                op[j] = f2bf(v);
            }
            *reinterpret_cast<ushort4*>(Wt + (size_t)n * 256 + kc * 4) = o;
        }
    }
}

// ---- scanA: per-512-chunk local exclusive scan -> loffs, chunk sum --------
__global__ void __launch_bounds__(512) scanA_kernel(
        const unsigned* __restrict__ counts,
        int* __restrict__ loffs,
        unsigned* __restrict__ bsums, int M) {
    int t = threadIdx.x;                 // 512 threads
    int i = blockIdx.x * 512 + t;
    unsigned c = (i < M) ? counts[i] : 0u;
    unsigned v = c;
    int lane = t & 63, w = t >> 6;
    #pragma unroll
    for (int d = 1; d < 64; d <<= 1) {
        unsigned n = __shfl_up(v, d);
        if (lane >= d) v += n;
    }
    __shared__ unsigned ws[8];
    if (lane == 63) ws[w] = v;
    __syncthreads();
    unsigned wb = 0;
    for (int k = 0; k < w; ++k) wb += ws[k];
    if (i < M) loffs[i] = (int)(wb + v - c);
    if (t == 511) bsums[blockIdx.x] = wb + v;    // block total
}

// ---- scanB: exclusive scan of the (<=256) chunk sums -> bbase -------------
__global__ void scanB_kernel(const unsigned* __restrict__ bsums,
                             int* __restrict__ bbase, int NB) {
    __shared__ unsigned s[256];
    int t = threadIdx.x;
    unsigned v = (t < NB) ? bsums[t] : 0u;
    s[t] = v;
    __syncthreads();
    for (int off = 1; off < 256; off <<= 1) {
        unsigned n = (t >= off) ? s[t - off] : 0u;
        __syncthreads();
        s[t] += n;
        __syncthreads();
    }
    if (t < NB) bbase[t] = (int)(s[t] - v);
}

// ---- scatter: pos = loffs[dst] + bbase[dst>>9] + rank ---------------------
__global__ void scatter_kernel(const int* __restrict__ e,
                               const int* __restrict__ loffs,
                               const int* __restrict__ bbase,
                               const int* __restrict__ rank,
                               int* __restrict__ csr, int E) {
    int i = blockIdx.x * blockDim.x + threadIdx.x;
    if (i < E) {
        int dst = e[E + i];
        csr[loffs[dst] + bbase[dst >> 9] + rank[i]] = e[i];
    }
}

// -------- 8-edge gather-min step for one row (2 edges/load, lane halves) ---
template<int XSB>
__device__ __forceinline__ void gstep(const float* xs_f,
                                      const unsigned short* xs_b,
                                      const int* csr, int p, int lim,
                                      int half, int cl, float4& mn) {
    int i0 = csr[min(p + 0, lim)];
    int i1 = csr[min(p + 1, lim)];
    int i2 = csr[min(p + 2, lim)];
    int i3 = csr[min(p + 3, lim)];
    int i4 = csr[min(p + 4, lim)];
    int i5 = csr[min(p + 5, lim)];
    int i6 = csr[min(p + 6, lim)];
    int i7 = csr[min(p + 7, lim)];
    int a0 = half ? i1 : i0;
    int a1 = half ? i3 : i2;
    int a2 = half ? i5 : i4;
    int a3 = half ? i7 : i6;
    float4 w0, w1, w2, w3;
    if (XSB) {
        uint2 u0 = *reinterpret_cast<const uint2*>(xs_b + (size_t)a0 * 128 + cl * 4);
        uint2 u1 = *reinterpret_cast<const uint2*>(xs_b + (size_t)a1 * 128 + cl * 4);
        uint2 u2 = *reinterpret_cast<const uint2*>(xs_b + (size_t)a2 * 128 + cl * 4);
        uint2 u3 = *reinterpret_cast<const uint2*>(xs_b + (size_t)a3 * 128 + cl * 4);
        w0 = upk(u0); w1 = upk(u1); w2 = upk(u2); w3 = upk(u3);
    } else {
        const float4* xs4 = reinterpret_cast<const float4*>(xs_f);
        w0 = xs4[(size_t)a0 * 32 + cl];
        w1 = xs4[(size_t)a1 * 32 + cl];
        w2 = xs4[(size_t)a2 * 32 + cl];
        w3 = xs4[(size_t)a3 * 32 + cl];
    }
    mn = fmin4(mn, fmin4(fmin4(w0, w1), fmin4(w2, w3)));
}

// ---------------- Fused (round-7 structure): gather-min -> LDS -> MFMA -----
template<int XSB>
__global__ __launch_bounds__(256, 4) void fused_kernel(
        const float* __restrict__ x_src,
        const unsigned short* __restrict__ xsb,
        const float* __restrict__ x_dst,
        const int* __restrict__ loffs,
        const int* __restrict__ bbase,
        const int* __restrict__ csr,
        const unsigned short* __restrict__ Wt,
        const float* __restrict__ bias,
        float* __restrict__ out, int M, int E) {
    __shared__ unsigned short At[FBM * 256];   // 32 KB
    char* Ab = reinterpret_cast<char*>(At);
    int tid = threadIdx.x;
    int lane = tid & 63;
    int wv = tid >> 6;
    int blockRow = blockIdx.x * FBM;

    #pragma unroll
    for (int i = 0; i < 8; ++i) {
        int u = tid + 256 * i;
        int lr = u >> 5;
        int c4 = u & 31;
        int gr = min(blockRow + lr, M - 1);
        float4 v = reinterpret_cast<const float4*>(x_dst)[(size_t)gr * 32 + c4];
        ushort4 o;
        o.x = f2bf(v.x); o.y = f2bf(v.y); o.z = f2bf(v.z); o.w = f2bf(v.w);
        *reinterpret_cast<ushort4*>(Ab + swz(lr, c4 * 8)) = o;
    }
    __syncthreads();

    int half = lane >> 5, cl = lane & 31;
    for (int j = 0; j < 4; ++j) {
        int lrb = wv * 16 + 4 * j;
        int beg0, beg1, beg2, beg3, end0, end1, end2, end3;
        {
            int r = __builtin_amdgcn_readfirstlane(blockRow + lrb);
            int g[5];
            #pragma unroll
            for (int k = 0; k < 5; ++k) {
                int x = r + k;
                g[k] = (x < M) ? (loffs[x] + bbase[x >> 9]) : E;
            }
            beg0 = (r + 0 < M) ? g[0] : 0;  end0 = (r + 0 < M) ? g[1] : 0;
            beg1 = (r + 1 < M) ? g[1] : 0;  end1 = (r + 1 < M) ? g[2] : 0;
            beg2 = (r + 2 < M) ? g[2] : 0;  end2 = (r + 2 < M) ? g[3] : 0;
            beg3 = (r + 3 < M) ? g[3] : 0;  end3 = (r + 3 < M) ? g[4] : 0;
        }
        float4 mn0 = make_float4(INFINITY, INFINITY, INFINITY, INFINITY);
        float4 mn1 = mn0, mn2 = mn0, mn3 = mn0;
        int p0 = beg0, p1 = beg1, p2 = beg2, p3 = beg3;
        while ((p0 < end0) | (p1 < end1) | (p2 < end2) | (p3 < end3)) {
            if (p0 < end0) { gstep<XSB>(x_src, xsb, csr, p0, end0 - 1, half, cl, mn0); p0 += 8; }
            if (p1 < end1) { gstep<XSB>(x_src, xsb, csr, p1, end1 - 1, half, cl, mn1); p1 += 8; }
            if (p2 < end2) { gstep<XSB>(x_src, xsb, csr, p2, end2 - 1, half, cl, mn2); p2 += 8; }
            if (p3 < end3) { gstep<XSB>(x_src, xsb, csr, p3, end3 - 1, half, cl, mn3); p3 += 8; }
        }
        mn0.x = fminf(mn0.x, __shfl_xor(mn0.x, 32));
        mn0.y = fminf(mn0.y, __shfl_xor(mn0.y, 32));
        mn0.z = fminf(mn0.z, __shfl_xor(mn0.z, 32));
        mn0.w = fminf(mn0.w, __shfl_xor(mn0.w, 32));
        mn1.x = fminf(mn1.x, __shfl_xor(mn1.x, 32));
        mn1.y = fminf(mn1.y, __shfl_xor(mn1.y, 32));
        mn1.z = fminf(mn1.z, __shfl_xor(mn1.z, 32));
        mn1.w = fminf(mn1.w, __shfl_xor(mn1.w, 32));
        mn2.x = fminf(mn2.x, __shfl_xor(mn2.x, 32));
        mn2.y = fminf(mn2.y, __shfl_xor(mn2.y, 32));
        mn2.z = fminf(mn2.z, __shfl_xor(mn2.z, 32));
        mn2.w = fminf(mn2.w, __shfl_xor(mn2.w, 32));
        mn3.x = fminf(mn3.x, __shfl_xor(mn3.x, 32));
        mn3.y = fminf(mn3.y, __shfl_xor(mn3.y, 32));
        mn3.z = fminf(mn3.z, __shfl_xor(mn3.z, 32));
        mn3.w = fminf(mn3.w, __shfl_xor(mn3.w, 32));

        {
            int lr = lrb + half;
            bool has = half ? (end1 > beg1) : (end0 > beg0);
            float4 m = half ? mn1 : mn0;
            ushort4 o;
            if (has) {
                o.x = f2bf(m.x); o.y = f2bf(m.y); o.z = f2bf(m.z); o.w = f2bf(m.w);
            } else {   // empty row: mn := xb  =>  h = xb@W0 exactly
                o = *reinterpret_cast<const ushort4*>(Ab + swz(lr, cl * 8));
            }
            *reinterpret_cast<ushort4*>(Ab + swz(lr, 256 + cl * 8)) = o;
        }
        {
            int lr = lrb + 2 + half;
            bool has = half ? (end3 > beg3) : (end2 > beg2);
            float4 m = half ? mn3 : mn2;
            ushort4 o;
            if (has) {
                o.x = f2bf(m.x); o.y = f2bf(m.y); o.z = f2bf(m.z); o.w = f2bf(m.w);
            } else {
                o = *reinterpret_cast<const ushort4*>(Ab + swz(lr, cl * 8));
            }
            *reinterpret_cast<ushort4*>(Ab + swz(lr, 256 + cl * 8)) = o;
        }
    }
    __syncthreads();

    int l15 = lane & 15;
    int q = lane >> 4;
    int ncol0 = wv * 32;

    f32x4 acc[4][2];
    #pragma unroll
    for (int t = 0; t < 4; ++t) {
        acc[t][0] = (f32x4){0.f, 0.f, 0.f, 0.f};
        acc[t][1] = (f32x4){0.f, 0.f, 0.f, 0.f};
    }
    size_t b0off = (size_t)(ncol0 + l15) * 256;
    size_t b1off = (size_t)(ncol0 + 16 + l15) * 256;

    #pragma unroll
    for (int s = 0; s < 8; ++s) {
        int koff = s * 32 + q * 8;
        short8 b0 = *reinterpret_cast<const short8*>(Wt + b0off + koff);
        short8 b1 = *reinterpret_cast<const short8*>(Wt + b1off + koff);
        #pragma unroll
        for (int t = 0; t < 4; ++t) {
            int lr = t * 16 + l15;
            short8 a = *reinterpret_cast<const short8*>(Ab + swz(lr, koff * 2));
            acc[t][0] = __builtin_amdgcn_mfma_f32_16x16x32_bf16(b0, a, acc[t][0], 0, 0, 0);
            acc[t][1] = __builtin_amdgcn_mfma_f32_16x16x32_bf16(b1, a, acc[t][1], 0, 0, 0);
        }
    }

    float4 bi[2];
    bi[0] = *reinterpret_cast<const float4*>(bias + ncol0 + q * 4);
    bi[1] = *reinterpret_cast<const float4*>(bias + ncol0 + 16 + q * 4);
    #pragma unroll
    for (int t = 0; t < 4; ++t) {
        int lr = t * 16 + l15;
        int row = blockRow + lr;
        if (row < M) {
            #pragma unroll
            for (int u = 0; u < 2; ++u) {
                int col = ncol0 + u * 16 + q * 4;
                uint2 xu = *reinterpret_cast<const uint2*>(Ab + swz(lr, col * 2));
                float4 xb = upk(xu);
                float4 o;
                float h;
                h = acc[t][u][0] + bi[u].x; o.x = xb.x + (h > 0.f ? h : SLOPE * h);
                h = acc[t][u][1] + bi[u].y; o.y = xb.y + (h > 0.f ? h : SLOPE * h);
                h = acc[t][u][2] + bi[u].z; o.z = xb.z + (h > 0.f ? h : SLOPE * h);
                h = acc[t][u][3] + bi[u].w; o.w = xb.w + (h > 0.f ? h : SLOPE * h);
                *reinterpret_cast<float4*>(out + (size_t)row * 128 + col) = o;
            }
        }
    }
}

extern "C" void kernel_launch(void* const* d_in, const int* in_sizes, int n_in,
                              void* d_out, int out_size, void* d_ws, size_t ws_size,
                              hipStream_t stream) {
    const float* x_src = (const float*)d_in[0];
    const float* x_dst = (const float*)d_in[1];
    const int*   e     = (const int*)d_in[2];
    const float* W     = (const float*)d_in[3];
    const float* bias  = (const float*)d_in[4];
    float* out = (float*)d_out;

    int NS = in_sizes[0] / WIDTH;   // 100000 src nodes
    int E  = in_sizes[2] / 2;       // 800000
    int M  = in_sizes[1] / WIDTH;   // 100000 dst nodes
    int NB = (M + 511) / 512;       // 196 (<= 256)

    // ws: xsb bf16[NS*128] | Wt bf16[128*256] | counts[M] | loffs[M] |
    //     rank[E] | csr[E] | bsums[NB] | bbase[NB]    (~33 MB)
    unsigned short* xsb = (unsigned short*)d_ws;
    unsigned short* Wt  = xsb + (size_t)NS * WIDTH;
    unsigned* counts  = (unsigned*)(Wt + 128 * 256);
    int*      loffs   = (int*)(counts + M);
    int*      rank    = loffs + M;
    int*      csr     = rank + E;
    unsigned* bsums   = (unsigned*)(csr + E);
    int*      bbase   = (int*)(bsums + NB);
    size_t need = (char*)(bbase + NB) - (char*)d_ws;
    int use_xsb = (ws_size >= need) ? 1 : 0;
    if (!use_xsb) {   // fallback: no xsb; shift layout to skip it
        Wt = (unsigned short*)d_ws;
        counts  = (unsigned*)(Wt + 128 * 256);
        loffs   = (int*)(counts + M);
        rank    = loffs + M;
        csr     = rank + E;
        bsums   = (unsigned*)(csr + E);
        bbase   = (int*)(bsums + NB);
    }

    hipMemsetAsync(counts, 0, (size_t)M * sizeof(unsigned), stream);

    int nconv = use_xsb ? (NS * 32 + 255) / 256 : 0;
    int nhist = (E + 255) / 256;
    int nwt   = (128 * 64 + 255) / 256;
    prep_kernel<<<nconv + nhist + nwt, 256, 0, stream>>>(x_src, W, e, xsb, Wt,
                                                         counts, rank, NS, E,
                                                         nconv, nhist);
    scanA_kernel<<<NB, 512, 0, stream>>>(counts, loffs, bsums, M);
    scanB_kernel<<<1, 256, 0, stream>>>(bsums, bbase, NB);
    scatter_kernel<<<(E + 255) / 256, 256, 0, stream>>>(e, loffs, bbase, rank,
                                                        csr, E);

    int fblocks = (M + FBM - 1) / FBM;   // 1563
    if (use_xsb)
        fused_kernel<1><<<fblocks, 256, 0, stream>>>(x_src, xsb, x_dst, loffs,
                                                     bbase, csr, Wt, bias, out,
                                                     M, E);
    else
        fused_kernel<0><<<fblocks, 256, 0, stream>>>(x_src, xsb, x_dst, loffs,
                                                     bbase, csr, Wt, bias, out,
                                                     M, E);
}